// Round 10
// baseline (369.425 us; speedup 1.0000x reference)
//
#include <hip/hip_runtime.h>
#include <math.h>

typedef __attribute__((ext_vector_type(8))) short bf16x8;
typedef __attribute__((ext_vector_type(4))) float f32x4;
typedef __attribute__((ext_vector_type(4))) int   i32x4;

__device__ inline unsigned short f2bf(float f) {
    unsigned u = __float_as_uint(f);
    u += 0x7fff + ((u >> 16) & 1);   // RNE (finite inputs)
    return (unsigned short)(u >> 16);
}
__device__ inline float bf2f(unsigned short h) {
    return __uint_as_float(((unsigned)h) << 16);
}
// pack two fp32 into one u32 of truncated bf16s: hi16=bf(a), lo16=bf(b)
__device__ inline unsigned pack_trunc(float a, float b) {
    return __builtin_amdgcn_perm(__float_as_uint(a), __float_as_uint(b), 0x07060302u);
}

__device__ inline void gload16(const void* g, void* l) {
    __builtin_amdgcn_global_load_lds(
        (const __attribute__((address_space(1))) unsigned int*)g,
        (__attribute__((address_space(3))) unsigned int*)l, 16, 0, 0);
}

// ---------------------------------------------------------------------------
// Convert fp32 -> split bf16 (hi/lo). Segments: q 2097152 | kv 4194304 |
// Wq,Wk,Wv,Wo 262144 each. Thread = one float4.
// ---------------------------------------------------------------------------
__global__ __launch_bounds__(256) void convert_split_kernel(
    const float* __restrict__ q, const float* __restrict__ kv,
    const float* __restrict__ Wq, const float* __restrict__ Wk,
    const float* __restrict__ Wv, const float* __restrict__ Wo,
    short* __restrict__ qhi, short* __restrict__ qlo,
    short* __restrict__ kvhi, short* __restrict__ kvlo,
    short* __restrict__ wqhi, short* __restrict__ wqlo,
    short* __restrict__ wkhi, short* __restrict__ wklo,
    short* __restrict__ wvhi, short* __restrict__ wvlo,
    short* __restrict__ wohi, short* __restrict__ wolo)
{
    int g = blockIdx.x * 256 + threadIdx.x;          // float4 index
    const float* src; short* dhi; short* dlo; int local;
    if      (g <  524288) { src = q;  dhi = qhi;  dlo = qlo;  local = g; }
    else if (g < 1572864) { src = kv; dhi = kvhi; dlo = kvlo; local = g -  524288; }
    else if (g < 1638400) { src = Wq; dhi = wqhi; dlo = wqlo; local = g - 1572864; }
    else if (g < 1703936) { src = Wk; dhi = wkhi; dlo = wklo; local = g - 1638400; }
    else if (g < 1769472) { src = Wv; dhi = wvhi; dlo = wvlo; local = g - 1703936; }
    else                  { src = Wo; dhi = wohi; dlo = wolo; local = g - 1769472; }
    float4 v = *(const float4*)(src + (size_t)local * 4);
    float f[4] = {v.x, v.y, v.z, v.w};
    short4 hi, lo;
    short* hp = (short*)&hi; short* lp = (short*)&lo;
    #pragma unroll
    for (int j = 0; j < 4; ++j) {
        unsigned short hb = f2bf(f[j]);
        hp[j] = (short)hb;
        lp[j] = (short)f2bf(f[j] - bf2f(hb));
    }
    *(short4*)(dhi + (size_t)local * 4) = hi;
    *(short4*)(dlo + (size_t)local * 4) = lo;
}

// ---------------------------------------------------------------------------
// Shared split-bf16 GEMM core: Y[m][n] = sum_k X[m][k] W[n][k] + bias[n].
// Block 128x128, 4 waves (2x2) of 64x64, BK=32, global_load_lds staging.
// ep: 0 = fp32 out; 1 = split bf16 out (scaled); 2 = bf16 out in attention
// PV B-fragment order (V path).
// ---------------------------------------------------------------------------
__device__ __forceinline__ void gemm_core(
    short* As_hi, short* As_lo, short* Bs_hi, short* Bs_lo,
    const short* __restrict__ Xhi, const short* __restrict__ Xlo,
    const short* __restrict__ Whi, const short* __restrict__ Wlo,
    const float* __restrict__ bias, float scale, int ep,
    float* __restrict__ outF, short* __restrict__ outHi, short* __restrict__ outLo,
    int m0, int n0)
{
    const int tid  = threadIdx.x;
    const int wave = tid >> 6, lane = tid & 63;
    const int quad = lane >> 4, col = lane & 15;
    const int wy = wave >> 1, wx = wave & 1;

    f32x4 acc[4][4];
    #pragma unroll
    for (int i = 0; i < 4; ++i)
        #pragma unroll
        for (int j = 0; j < 4; ++j) acc[i][j] = (f32x4){0.f, 0.f, 0.f, 0.f};

    int aoff[4], boff[4];
    #pragma unroll
    for (int t = 0; t < 4; ++t) {
        aoff[t] = (wy * 64 + t * 16 + col) * 32 + quad * 8;
        boff[t] = (wx * 64 + t * 16 + col) * 32 + quad * 8;
    }

    const short* Abase_hi = Xhi + (size_t)m0 * 512;
    const short* Abase_lo = Xlo + (size_t)m0 * 512;
    const short* Bbase_hi = Whi + (size_t)n0 * 512;
    const short* Bbase_lo = Wlo + (size_t)n0 * 512;

    for (int kb = 0; kb < 512; kb += 32) {
        __syncthreads();
        #pragma unroll
        for (int i = 0; i < 2; ++i) {
            int p = i * 256 + tid;
            int r = p >> 2, qq = p & 3;
            size_t go = (size_t)r * 512 + kb + qq * 8;
            int lb = (i * 256 + wave * 64) * 8;   // wave-uniform LDS base
            gload16(Abase_hi + go, &As_hi[lb]);
            gload16(Abase_lo + go, &As_lo[lb]);
            gload16(Bbase_hi + go, &Bs_hi[lb]);
            gload16(Bbase_lo + go, &Bs_lo[lb]);
        }
        __syncthreads();

        bf16x8 ah[4], al[4], bh[4], bl[4];
        #pragma unroll
        for (int t = 0; t < 4; ++t) {
            ah[t] = *(const bf16x8*)&As_hi[aoff[t]];
            al[t] = *(const bf16x8*)&As_lo[aoff[t]];
            bh[t] = *(const bf16x8*)&Bs_hi[boff[t]];
            bl[t] = *(const bf16x8*)&Bs_lo[boff[t]];
        }
        #pragma unroll
        for (int tm = 0; tm < 4; ++tm)
            #pragma unroll
            for (int tn = 0; tn < 4; ++tn) {
                acc[tm][tn] = __builtin_amdgcn_mfma_f32_16x16x32_bf16(ah[tm], bh[tn], acc[tm][tn], 0, 0, 0);
                acc[tm][tn] = __builtin_amdgcn_mfma_f32_16x16x32_bf16(al[tm], bh[tn], acc[tm][tn], 0, 0, 0);
                acc[tm][tn] = __builtin_amdgcn_mfma_f32_16x16x32_bf16(ah[tm], bl[tn], acc[tm][tn], 0, 0, 0);
            }
    }

    #pragma unroll
    for (int tn = 0; tn < 4; ++tn) {
        int ng = n0 + wx * 64 + tn * 16 + col;
        float bb = bias[ng];
        #pragma unroll
        for (int tm = 0; tm < 4; ++tm) {
            int mb = m0 + wy * 64 + tm * 16 + quad * 4;
            if (ep == 2) {
                // V-fragment order: per (b,h,128-kv-tile):
                // [sw][dt][flane=qd*16+d15][j8 = kv&3 | t01*4]
                int bb_ = mb >> 12, kvg = mb & 4095;
                int tile = kvg >> 7, kv128 = kvg & 127;
                int t01 = (kv128 >> 6) & 1, sw = (kv128 >> 4) & 3, qd = (kv128 >> 2) & 3;
                int hh = ng >> 6, dd = ng & 63, dt = dd >> 4, d15 = dd & 15;
                size_t base = ((((size_t)((bb_ * 8 + hh) * 32 + tile) * 16)
                               + sw * 4 + dt) * 64 + qd * 16 + d15) * 8 + t01 * 4;
                short4 s4; short* sp = (short*)&s4;
                #pragma unroll
                for (int r = 0; r < 4; ++r) sp[r] = (short)f2bf(acc[tm][tn][r] + bb);
                *(short4*)&outHi[base] = s4;
            } else {
                #pragma unroll
                for (int r = 0; r < 4; ++r) {
                    float val = acc[tm][tn][r] + bb;
                    if (ep == 0) {
                        outF[(size_t)(mb + r) * 512 + ng] = val;
                    } else {
                        val *= scale;
                        unsigned short hb = f2bf(val);
                        outHi[(size_t)(mb + r) * 512 + ng] = (short)hb;
                        outLo[(size_t)(mb + r) * 512 + ng] = (short)f2bf(val - bf2f(hb));
                    }
                }
            }
        }
    }
}

// Fused Q/K/V projections: blocks [0,128) Q | [128,384) K | [384,640) V.
__global__ __launch_bounds__(256) void fused_qkv_gemm_kernel(
    const short* __restrict__ cq_hi, const short* __restrict__ cq_lo,
    const short* __restrict__ ckv_hi, const short* __restrict__ ckv_lo,
    const short* __restrict__ wq_hi, const short* __restrict__ wq_lo,
    const short* __restrict__ wk_hi, const short* __restrict__ wk_lo,
    const short* __restrict__ wv_hi, const short* __restrict__ wv_lo,
    const float* __restrict__ bq, const float* __restrict__ bk,
    const float* __restrict__ bv, float qscale,
    short* __restrict__ Qhi, short* __restrict__ Qlo,
    short* __restrict__ Khi, short* __restrict__ Klo,
    short* __restrict__ Vfrag)
{
    __shared__ short As_hi[128 * 32], As_lo[128 * 32];
    __shared__ short Bs_hi[128 * 32], Bs_lo[128 * 32];

    int bi = blockIdx.x;
    const short *Xhi, *Xlo, *Whi, *Wlo; const float* bias;
    float scale = 1.0f; int ep;
    short *oHi = nullptr, *oLo = nullptr;
    if (bi < 128) {
        Xhi = cq_hi;  Xlo = cq_lo;  Whi = wq_hi; Wlo = wq_lo; bias = bq;
        scale = qscale; ep = 1; oHi = Qhi; oLo = Qlo;
    } else if (bi < 384) {
        bi -= 128;
        Xhi = ckv_hi; Xlo = ckv_lo; Whi = wk_hi; Wlo = wk_lo; bias = bk;
        ep = 1; oHi = Khi; oLo = Klo;
    } else {
        bi -= 384;
        Xhi = ckv_hi; Xlo = ckv_lo; Whi = wv_hi; Wlo = wv_lo; bias = bv;
        ep = 2; oHi = Vfrag;
    }
    int m0 = (bi >> 2) * 128, n0 = (bi & 3) * 128;
    gemm_core(As_hi, As_lo, Bs_hi, Bs_lo, Xhi, Xlo, Whi, Wlo, bias, scale, ep,
              nullptr, oHi, oLo, m0, n0);
}

// O-projection: fp32 out.
__global__ __launch_bounds__(256) void gemm_o_kernel(
    const short* __restrict__ Xhi, const short* __restrict__ Xlo,
    const short* __restrict__ Whi, const short* __restrict__ Wlo,
    const float* __restrict__ bias, float* __restrict__ outF)
{
    __shared__ short As_hi[128 * 32], As_lo[128 * 32];
    __shared__ short Bs_hi[128 * 32], Bs_lo[128 * 32];
    int m0 = (int)(blockIdx.x >> 2) * 128, n0 = (int)(blockIdx.x & 3) * 128;
    gemm_core(As_hi, As_lo, Bs_hi, Bs_lo, Xhi, Xlo, Whi, Wlo, bias, 1.0f, 0,
              outF, nullptr, nullptr, m0, n0);
}

// ---------------------------------------------------------------------------
// RoPE on split-bf16 K, in place, with per-block LDS sin/cos table:
// each block covers 4 rows x 32 freqs -> only 128 sincosf per block
// (threads 0..127), 8x less trig than per-element evaluation.
// ---------------------------------------------------------------------------
__global__ __launch_bounds__(256) void rope_kernel(short* __restrict__ Khi,
                                                   short* __restrict__ Klo)
{
    __shared__ float2 tbl[4][32];
    const int t = threadIdx.x;
    const int g = blockIdx.x * 256 + t;     // 524288 total
    if (t < 128) {
        int p = t >> 5, i = t & 31;
        int pos = (blockIdx.x * 4 + p) & 4095;
        float fr = expf((float)i * -0.28782313662425576f);
        float sv, cv;
        sincosf((float)pos * fr, &sv, &cv);
        tbl[p][i] = make_float2(cv, sv);
    }
    __syncthreads();

    int row = g >> 6;
    int c8  = (g & 63) * 8;
    size_t off = (size_t)row * 512 + c8;
    bf16x8 hi = *(const bf16x8*)&Khi[off];
    bf16x8 lo = *(const bf16x8*)&Klo[off];
    float x[8];
    #pragma unroll
    for (int j = 0; j < 8; ++j)
        x[j] = bf2f((unsigned short)hi[j]) + bf2f((unsigned short)lo[j]);
    const int rl = row & 3;
    const int ib = (c8 & 63) >> 1;
    #pragma unroll
    for (int p = 0; p < 4; ++p) {
        float2 cs = tbl[rl][ib + p];
        float e = x[2 * p], o = x[2 * p + 1];
        x[2 * p]     = e * cs.x - o * cs.y;
        x[2 * p + 1] = o * cs.x + e * cs.y;
    }
    #pragma unroll
    for (int j = 0; j < 8; ++j) {
        unsigned short hb = f2bf(x[j]);
        hi[j] = (short)hb;
        lo[j] = (short)f2bf(x[j] - bf2f(hb));
    }
    *(bf16x8*)&Khi[off] = hi;
    *(bf16x8*)&Klo[off] = lo;
}

// ---------------------------------------------------------------------------
// MFMA flash attention v9: 3 blocks/CU.
//  - K-hi staged via wave-private global_load_lds double-buffer (16 KB/wave
//    halved to 8 KB: hi only) + explicit vmcnt(0) drain (R8-proven).
//  - K-lo + V as plain register loads (compiler-waited); the 16 hi-only QK
//    MFMAs are issued first so matrix work covers the lo loads' latency.
//  - LDS 34 KB total (staging unioned with reduction buffers) and
//    __launch_bounds__(256,3): 12 waves/CU (was 8).
//  - R9 compute tricks kept: QK-before-exp, perm-pack P, ones-column li.
// ---------------------------------------------------------------------------
__global__ __launch_bounds__(256, 3) void attn_mfma_kernel(
    const short* __restrict__ Qhi, const short* __restrict__ Qlo,
    const short* __restrict__ Khi, const short* __restrict__ Klo,
    const short* __restrict__ Vfrag,
    short* __restrict__ AOhi, short* __restrict__ AOlo)
{
    __shared__ char smem[34816];   // staging [0,32768): wave*8 KB (2x4 KB
                                   // parity); after loop: Opart+Lpart overlay

    const int tid  = threadIdx.x;
    const int wave = tid >> 6;
    const int lane = tid & 63;
    const int quad = lane >> 4;
    const int l15  = lane & 15;

    const int bh = blockIdx.x & 15;      // XCD-local: blk%8 == h under RR
    const int qt = blockIdx.x >> 4;
    const int b  = bh >> 3, h = bh & 7;
    const int qb = qt * 64;

    // ---- Q as B-fragments (all 64 q rows), hi/lo ----
    bf16x8 qh[4][2], ql[4][2];
    #pragma unroll
    for (int tq = 0; tq < 4; ++tq)
        #pragma unroll
        for (int c = 0; c < 2; ++c) {
            size_t qo = ((size_t)(b * 2048 + qb + tq * 16 + l15)) * 512
                        + h * 64 + c * 32 + quad * 8;
            qh[tq][c] = *(const bf16x8*)&Qhi[qo];
            ql[tq][c] = *(const bf16x8*)&Qlo[qo];
        }

    f32x4 o[4][4];    // [tq][dt] O partials over this wave's kv
    f32x4 lo4[4];     // [tq] row sums (ones-column PV)
    #pragma unroll
    for (int i = 0; i < 4; ++i) {
        lo4[i] = (f32x4){0.f, 0.f, 0.f, 0.f};
        #pragma unroll
        for (int j = 0; j < 4; ++j) o[i][j] = (f32x4){0.f, 0.f, 0.f, 0.f};
    }

    const i32x4 onesw = (i32x4){0x3F803F80, 0x3F803F80, 0x3F803F80, 0x3F803F80};
    const bf16x8 vones = *(const bf16x8*)&onesw;

    // per-lane K global bases (this wave's kv rows)
    const short* kh_p = Khi + ((size_t)(b * 4096 + wave * 16 + l15)) * 512
                        + h * 64 + quad * 8;
    const short* klr  = Klo + ((size_t)(b * 4096 + wave * 16 + l15)) * 512
                        + h * 64 + quad * 8;
    const short* v_p = Vfrag + ((size_t)(b * 8 + h)) * 32 * 8192
                       + ((size_t)(wave * 4) * 64 + lane) * 8;

    // wave-private K-hi staging (shorts): parity p at +p*2048, frag f at
    // +f*512 (f = s*2 + c), lane reads/lands at +lane*8.
    short* sw_base = (short*)smem + wave * 4096;

    // ---- prologue: stage it=0 K-hi into parity 0 ----
    #pragma unroll
    for (int s = 0; s < 2; ++s)
        #pragma unroll
        for (int c = 0; c < 2; ++c)
            gload16(kh_p + (size_t)(s * 64) * 512 + c * 32,
                    sw_base + (s * 2 + c) * 512);

    for (int it = 0; it < 32; ++it) {
        const int parity = it & 1;
        short* kb = sw_base + parity * 2048;

        // drain this wave's staging DMAs (LDS-dest, not auto-waited)
        __builtin_amdgcn_s_waitcnt(0x0F70);   // vmcnt(0)

        bf16x8 k0h[2], k1h[2];
        #pragma unroll
        for (int c = 0; c < 2; ++c) {
            k0h[c] = *(const bf16x8*)(kb + (0 + c) * 512 + lane * 8);
            k1h[c] = *(const bf16x8*)(kb + (2 + c) * 512 + lane * 8);
        }

        // K-lo + V register loads (compiler inserts vmcnt before use)
        bf16x8 k0l[2], k1l[2], vf[4];
        #pragma unroll
        for (int c = 0; c < 2; ++c) {
            k0l[c] = *(const bf16x8*)(klr + c * 32);
            k1l[c] = *(const bf16x8*)(klr + (size_t)64 * 512 + c * 32);
        }
        #pragma unroll
        for (int dt = 0; dt < 4; ++dt)
            vf[dt] = *(const bf16x8*)(v_p + dt * 512);

        // async K-hi staging for it+1 into other parity
        if (it + 1 < 32) {
            const short* khn = kh_p + (size_t)(it + 1) * 128 * 512;
            short* nb = sw_base + (parity ^ 1) * 2048;
            #pragma unroll
            for (int s = 0; s < 2; ++s)
                #pragma unroll
                for (int c = 0; c < 2; ++c)
                    gload16(khn + (size_t)(s * 64) * 512 + c * 32,
                            nb + (s * 2 + c) * 512);
        }

        // ---- QK MFMAs: all hi-only products first (cover K-lo latency) ----
        f32x4 s0[4], s1[4];
        #pragma unroll
        for (int t = 0; t < 4; ++t) {
            s0[t] = (f32x4){0.f, 0.f, 0.f, 0.f};
            s1[t] = (f32x4){0.f, 0.f, 0.f, 0.f};
        }
        #pragma unroll
        for (int c = 0; c < 2; ++c)
            #pragma unroll
            for (int tq = 0; tq < 4; ++tq) {
                s0[tq] = __builtin_amdgcn_mfma_f32_16x16x32_bf16(k0h[c], qh[tq][c], s0[tq], 0, 0, 0);
                s1[tq] = __builtin_amdgcn_mfma_f32_16x16x32_bf16(k1h[c], qh[tq][c], s1[tq], 0, 0, 0);
            }
        #pragma unroll
        for (int c = 0; c < 2; ++c)
            #pragma unroll
            for (int tq = 0; tq < 4; ++tq) {
                s0[tq] = __builtin_amdgcn_mfma_f32_16x16x32_bf16(k0h[c], ql[tq][c], s0[tq], 0, 0, 0);
                s1[tq] = __builtin_amdgcn_mfma_f32_16x16x32_bf16(k1h[c], ql[tq][c], s1[tq], 0, 0, 0);
            }
        #pragma unroll
        for (int c = 0; c < 2; ++c)
            #pragma unroll
            for (int tq = 0; tq < 4; ++tq) {
                s0[tq] = __builtin_amdgcn_mfma_f32_16x16x32_bf16(k0l[c], qh[tq][c], s0[tq], 0, 0, 0);
                s1[tq] = __builtin_amdgcn_mfma_f32_16x16x32_bf16(k1l[c], qh[tq][c], s1[tq], 0, 0, 0);
            }

        // ---- exp2 + perm-pack + PV (per tq) ----
        #pragma unroll
        for (int tq = 0; tq < 4; ++tq) {
            float e0 = exp2f(s0[tq][0]), e1 = exp2f(s0[tq][1]);
            float e2 = exp2f(s0[tq][2]), e3 = exp2f(s0[tq][3]);
            float e4 = exp2f(s1[tq][0]), e5 = exp2f(s1[tq][1]);
            float e6 = exp2f(s1[tq][2]), e7 = exp2f(s1[tq][3]);
            i32x4 pw;
            pw.x = pack_trunc(e1, e0);
            pw.y = pack_trunc(e3, e2);
            pw.z = pack_trunc(e5, e4);
            pw.w = pack_trunc(e7, e6);
            bf16x8 p8 = *(bf16x8*)&pw;
            #pragma unroll
            for (int dt = 0; dt < 4; ++dt)
                o[tq][dt] = __builtin_amdgcn_mfma_f32_16x16x32_bf16(p8, vf[dt], o[tq][dt], 0, 0, 0);
            lo4[tq] = __builtin_amdgcn_mfma_f32_16x16x32_bf16(p8, vones, lo4[tq], 0, 0, 0);
        }

        klr += (size_t)128 * 512;
        v_p += 8192;
    }

    __syncthreads();   // staging LDS dead; reuse as reduction buffers
    float* Opart = (float*)smem;               // [4][64*33]
    float* Lpart = (float*)(smem + 33792);     // [4][64]

    // ---- two-pass cross-wave O reduction (pass 0: d 0..31, pass 1: 32..63) ----
    float inv_save[8];
    #pragma unroll
    for (int pass = 0; pass < 2; ++pass) {
        if (pass) __syncthreads();          // prior reads complete
        #pragma unroll
        for (int tq = 0; tq < 4; ++tq)
            #pragma unroll
            for (int dh = 0; dh < 2; ++dh) {
                int dt = pass * 2 + dh;
                #pragma unroll
                for (int r = 0; r < 4; ++r)
                    Opart[wave * (64 * 33) + (tq * 16 + quad * 4 + r) * 33 + dh * 16 + l15] = o[tq][dt][r];
            }
        if (pass == 0 && l15 == 0) {
            #pragma unroll
            for (int tq = 0; tq < 4; ++tq)
                #pragma unroll
                for (int r = 0; r < 4; ++r)
                    Lpart[wave * 64 + tq * 16 + quad * 4 + r] = lo4[tq][r];
        }
        __syncthreads();
        #pragma unroll
        for (int r = 0; r < 8; ++r) {
            int qq = wave * 16 + r * 2 + (lane >> 5);
            int d  = lane & 31;
            float v = Opart[0 * (64 * 33) + qq * 33 + d] + Opart[1 * (64 * 33) + qq * 33 + d]
                    + Opart[2 * (64 * 33) + qq * 33 + d] + Opart[3 * (64 * 33) + qq * 33 + d];
            float inv;
            if (pass == 0) {
                float l = Lpart[qq] + Lpart[64 + qq] + Lpart[128 + qq] + Lpart[192 + qq];
                inv = 1.0f / l;
                inv_save[r] = inv;
            } else {
                inv = inv_save[r];
            }
            float val = v * inv;
            unsigned short hb = f2bf(val);
            size_t oo = ((size_t)(b * 2048 + qb + qq)) * 512 + h * 64 + pass * 32 + d;
            AOhi[oo] = (short)hb;
            AOlo[oo] = (short)f2bf(val - bf2f(hb));
        }
    }
}

// ---------------------------------------------------------------------------
extern "C" void kernel_launch(void* const* d_in, const int* in_sizes, int n_in,
                              void* d_out, int out_size, void* d_ws, size_t ws_size,
                              hipStream_t stream) {
    const float* q  = (const float*)d_in[0];
    const float* kv = (const float*)d_in[1];
    const float* Wq = (const float*)d_in[2];
    const float* bq = (const float*)d_in[3];
    const float* Wk = (const float*)d_in[4];
    const float* bk = (const float*)d_in[5];
    const float* Wv = (const float*)d_in[6];
    const float* bv = (const float*)d_in[7];
    const float* Wo = (const float*)d_in[8];
    const float* bo = (const float*)d_in[9];
    float* out = (float*)d_out;

    char* ws = (char*)d_ws;
    const size_t MB = 1024 * 1024;
    short* cq_hi  = (short*)(ws + 0 * MB);
    short* cq_lo  = (short*)(ws + 4 * MB);
    short* ckv_hi = (short*)(ws + 8 * MB);
    short* ckv_lo = (short*)(ws + 16 * MB);
    short* wq_hi  = (short*)(ws + 24 * MB); short* wq_lo = wq_hi + 262144;
    short* wk_hi  = (short*)(ws + 25 * MB); short* wk_lo = wk_hi + 262144;
    short* wv_hi  = (short*)(ws + 26 * MB); short* wv_lo = wv_hi + 262144;
    short* wo_hi  = (short*)(ws + 27 * MB); short* wo_lo = wo_hi + 262144;
    short* Qhi    = (short*)(ws + 28 * MB);
    short* Qlo    = (short*)(ws + 32 * MB);
    short* Khi    = (short*)(ws + 36 * MB);
    short* Klo    = (short*)(ws + 44 * MB);
    short* Vfrag  = (short*)(ws + 52 * MB);
    short* AOhi   = (short*)(ws + 0 * MB);   // overlay dead converted-q
    short* AOlo   = (short*)(ws + 4 * MB);

    // 0.125 (1/sqrt(Dh)) * log2(e), so attention exp is a bare exp2.
    const float qscale = 0.18033688011112043f;

    dim3 blk(256);
    convert_split_kernel<<<7168, blk, 0, stream>>>(
        q, kv, Wq, Wk, Wv, Wo,
        cq_hi, cq_lo, ckv_hi, ckv_lo,
        wq_hi, wq_lo, wk_hi, wk_lo, wv_hi, wv_lo, wo_hi, wo_lo);

    fused_qkv_gemm_kernel<<<640, blk, 0, stream>>>(
        cq_hi, cq_lo, ckv_hi, ckv_lo,
        wq_hi, wq_lo, wk_hi, wk_lo, wv_hi, wv_lo,
        bq, bk, bv, qscale,
        Qhi, Qlo, Khi, Klo, Vfrag);

    rope_kernel<<<2048, blk, 0, stream>>>(Khi, Klo);

    attn_mfma_kernel<<<dim3(512), blk, 0, stream>>>(
        Qhi, Qlo, Khi, Klo, Vfrag, AOhi, AOlo);

    gemm_o_kernel<<<128, blk, 0, stream>>>(
        AOhi, AOlo, wo_hi, wo_lo, bo, out);
}

// Round 11
// 251.728 us; speedup vs baseline: 1.4676x; 1.4676x over previous
//
#include <hip/hip_runtime.h>
#include <math.h>

typedef __attribute__((ext_vector_type(8))) short bf16x8;
typedef __attribute__((ext_vector_type(4))) float f32x4;
typedef __attribute__((ext_vector_type(4))) int   i32x4;

__device__ inline unsigned short f2bf(float f) {
    unsigned u = __float_as_uint(f);
    u += 0x7fff + ((u >> 16) & 1);   // RNE (finite inputs)
    return (unsigned short)(u >> 16);
}
__device__ inline float bf2f(unsigned short h) {
    return __uint_as_float(((unsigned)h) << 16);
}
// pack two fp32 into one u32 of truncated bf16s: hi16=bf(a), lo16=bf(b)
__device__ inline unsigned pack_trunc(float a, float b) {
    return __builtin_amdgcn_perm(__float_as_uint(a), __float_as_uint(b), 0x07060302u);
}

__device__ inline void gload16(const void* g, void* l) {
    __builtin_amdgcn_global_load_lds(
        (const __attribute__((address_space(1))) unsigned int*)g,
        (__attribute__((address_space(3))) unsigned int*)l, 16, 0, 0);
}

// ---------------------------------------------------------------------------
// Convert fp32 -> split bf16 (hi/lo). Segments: q 2097152 | kv 4194304 |
// Wq,Wk,Wv,Wo 262144 each. Thread = one float4.
// ---------------------------------------------------------------------------
__global__ __launch_bounds__(256) void convert_split_kernel(
    const float* __restrict__ q, const float* __restrict__ kv,
    const float* __restrict__ Wq, const float* __restrict__ Wk,
    const float* __restrict__ Wv, const float* __restrict__ Wo,
    short* __restrict__ qhi, short* __restrict__ qlo,
    short* __restrict__ kvhi, short* __restrict__ kvlo,
    short* __restrict__ wqhi, short* __restrict__ wqlo,
    short* __restrict__ wkhi, short* __restrict__ wklo,
    short* __restrict__ wvhi, short* __restrict__ wvlo,
    short* __restrict__ wohi, short* __restrict__ wolo)
{
    int g = blockIdx.x * 256 + threadIdx.x;          // float4 index
    const float* src; short* dhi; short* dlo; int local;
    if      (g <  524288) { src = q;  dhi = qhi;  dlo = qlo;  local = g; }
    else if (g < 1572864) { src = kv; dhi = kvhi; dlo = kvlo; local = g -  524288; }
    else if (g < 1638400) { src = Wq; dhi = wqhi; dlo = wqlo; local = g - 1572864; }
    else if (g < 1703936) { src = Wk; dhi = wkhi; dlo = wklo; local = g - 1638400; }
    else if (g < 1769472) { src = Wv; dhi = wvhi; dlo = wvlo; local = g - 1703936; }
    else                  { src = Wo; dhi = wohi; dlo = wolo; local = g - 1769472; }
    float4 v = *(const float4*)(src + (size_t)local * 4);
    float f[4] = {v.x, v.y, v.z, v.w};
    short4 hi, lo;
    short* hp = (short*)&hi; short* lp = (short*)&lo;
    #pragma unroll
    for (int j = 0; j < 4; ++j) {
        unsigned short hb = f2bf(f[j]);
        hp[j] = (short)hb;
        lp[j] = (short)f2bf(f[j] - bf2f(hb));
    }
    *(short4*)(dhi + (size_t)local * 4) = hi;
    *(short4*)(dlo + (size_t)local * 4) = lo;
}

// ---------------------------------------------------------------------------
// Shared split-bf16 GEMM core: Y[m][n] = sum_k X[m][k] W[n][k] + bias[n].
// Block 128x128, 4 waves (2x2) of 64x64, BK=32, global_load_lds staging.
// ep: 0 = fp32 out; 1 = split bf16 out (scaled); 2 = bf16 out in attention
// PV B-fragment order (V path).
// ---------------------------------------------------------------------------
__device__ __forceinline__ void gemm_core(
    short* As_hi, short* As_lo, short* Bs_hi, short* Bs_lo,
    const short* __restrict__ Xhi, const short* __restrict__ Xlo,
    const short* __restrict__ Whi, const short* __restrict__ Wlo,
    const float* __restrict__ bias, float scale, int ep,
    float* __restrict__ outF, short* __restrict__ outHi, short* __restrict__ outLo,
    int m0, int n0)
{
    const int tid  = threadIdx.x;
    const int wave = tid >> 6, lane = tid & 63;
    const int quad = lane >> 4, col = lane & 15;
    const int wy = wave >> 1, wx = wave & 1;

    f32x4 acc[4][4];
    #pragma unroll
    for (int i = 0; i < 4; ++i)
        #pragma unroll
        for (int j = 0; j < 4; ++j) acc[i][j] = (f32x4){0.f, 0.f, 0.f, 0.f};

    int aoff[4], boff[4];
    #pragma unroll
    for (int t = 0; t < 4; ++t) {
        aoff[t] = (wy * 64 + t * 16 + col) * 32 + quad * 8;
        boff[t] = (wx * 64 + t * 16 + col) * 32 + quad * 8;
    }

    const short* Abase_hi = Xhi + (size_t)m0 * 512;
    const short* Abase_lo = Xlo + (size_t)m0 * 512;
    const short* Bbase_hi = Whi + (size_t)n0 * 512;
    const short* Bbase_lo = Wlo + (size_t)n0 * 512;

    for (int kb = 0; kb < 512; kb += 32) {
        __syncthreads();
        #pragma unroll
        for (int i = 0; i < 2; ++i) {
            int p = i * 256 + tid;
            int r = p >> 2, qq = p & 3;
            size_t go = (size_t)r * 512 + kb + qq * 8;
            int lb = (i * 256 + wave * 64) * 8;   // wave-uniform LDS base
            gload16(Abase_hi + go, &As_hi[lb]);
            gload16(Abase_lo + go, &As_lo[lb]);
            gload16(Bbase_hi + go, &Bs_hi[lb]);
            gload16(Bbase_lo + go, &Bs_lo[lb]);
        }
        __syncthreads();

        bf16x8 ah[4], al[4], bh[4], bl[4];
        #pragma unroll
        for (int t = 0; t < 4; ++t) {
            ah[t] = *(const bf16x8*)&As_hi[aoff[t]];
            al[t] = *(const bf16x8*)&As_lo[aoff[t]];
            bh[t] = *(const bf16x8*)&Bs_hi[boff[t]];
            bl[t] = *(const bf16x8*)&Bs_lo[boff[t]];
        }
        #pragma unroll
        for (int tm = 0; tm < 4; ++tm)
            #pragma unroll
            for (int tn = 0; tn < 4; ++tn) {
                acc[tm][tn] = __builtin_amdgcn_mfma_f32_16x16x32_bf16(ah[tm], bh[tn], acc[tm][tn], 0, 0, 0);
                acc[tm][tn] = __builtin_amdgcn_mfma_f32_16x16x32_bf16(al[tm], bh[tn], acc[tm][tn], 0, 0, 0);
                acc[tm][tn] = __builtin_amdgcn_mfma_f32_16x16x32_bf16(ah[tm], bl[tn], acc[tm][tn], 0, 0, 0);
            }
    }

    #pragma unroll
    for (int tn = 0; tn < 4; ++tn) {
        int ng = n0 + wx * 64 + tn * 16 + col;
        float bb = bias[ng];
        #pragma unroll
        for (int tm = 0; tm < 4; ++tm) {
            int mb = m0 + wy * 64 + tm * 16 + quad * 4;
            if (ep == 2) {
                // V-fragment order: per (b,h,128-kv-tile):
                // [sw][dt][flane=qd*16+d15][j8 = kv&3 | t01*4]
                int bb_ = mb >> 12, kvg = mb & 4095;
                int tile = kvg >> 7, kv128 = kvg & 127;
                int t01 = (kv128 >> 6) & 1, sw = (kv128 >> 4) & 3, qd = (kv128 >> 2) & 3;
                int hh = ng >> 6, dd = ng & 63, dt = dd >> 4, d15 = dd & 15;
                size_t base = ((((size_t)((bb_ * 8 + hh) * 32 + tile) * 16)
                               + sw * 4 + dt) * 64 + qd * 16 + d15) * 8 + t01 * 4;
                short4 s4; short* sp = (short*)&s4;
                #pragma unroll
                for (int r = 0; r < 4; ++r) sp[r] = (short)f2bf(acc[tm][tn][r] + bb);
                *(short4*)&outHi[base] = s4;
            } else {
                #pragma unroll
                for (int r = 0; r < 4; ++r) {
                    float val = acc[tm][tn][r] + bb;
                    if (ep == 0) {
                        outF[(size_t)(mb + r) * 512 + ng] = val;
                    } else {
                        val *= scale;
                        unsigned short hb = f2bf(val);
                        outHi[(size_t)(mb + r) * 512 + ng] = (short)hb;
                        outLo[(size_t)(mb + r) * 512 + ng] = (short)f2bf(val - bf2f(hb));
                    }
                }
            }
        }
    }
}

// Fused Q/K/V projections: blocks [0,128) Q | [128,384) K | [384,640) V.
__global__ __launch_bounds__(256) void fused_qkv_gemm_kernel(
    const short* __restrict__ cq_hi, const short* __restrict__ cq_lo,
    const short* __restrict__ ckv_hi, const short* __restrict__ ckv_lo,
    const short* __restrict__ wq_hi, const short* __restrict__ wq_lo,
    const short* __restrict__ wk_hi, const short* __restrict__ wk_lo,
    const short* __restrict__ wv_hi, const short* __restrict__ wv_lo,
    const float* __restrict__ bq, const float* __restrict__ bk,
    const float* __restrict__ bv, float qscale,
    short* __restrict__ Qhi, short* __restrict__ Qlo,
    short* __restrict__ Khi, short* __restrict__ Klo,
    short* __restrict__ Vfrag)
{
    __shared__ short As_hi[128 * 32], As_lo[128 * 32];
    __shared__ short Bs_hi[128 * 32], Bs_lo[128 * 32];

    int bi = blockIdx.x;
    const short *Xhi, *Xlo, *Whi, *Wlo; const float* bias;
    float scale = 1.0f; int ep;
    short *oHi = nullptr, *oLo = nullptr;
    if (bi < 128) {
        Xhi = cq_hi;  Xlo = cq_lo;  Whi = wq_hi; Wlo = wq_lo; bias = bq;
        scale = qscale; ep = 1; oHi = Qhi; oLo = Qlo;
    } else if (bi < 384) {
        bi -= 128;
        Xhi = ckv_hi; Xlo = ckv_lo; Whi = wk_hi; Wlo = wk_lo; bias = bk;
        ep = 1; oHi = Khi; oLo = Klo;
    } else {
        bi -= 384;
        Xhi = ckv_hi; Xlo = ckv_lo; Whi = wv_hi; Wlo = wv_lo; bias = bv;
        ep = 2; oHi = Vfrag;
    }
    int m0 = (bi >> 2) * 128, n0 = (bi & 3) * 128;
    gemm_core(As_hi, As_lo, Bs_hi, Bs_lo, Xhi, Xlo, Whi, Wlo, bias, scale, ep,
              nullptr, oHi, oLo, m0, n0);
}

// O-projection: fp32 out.
__global__ __launch_bounds__(256) void gemm_o_kernel(
    const short* __restrict__ Xhi, const short* __restrict__ Xlo,
    const short* __restrict__ Whi, const short* __restrict__ Wlo,
    const float* __restrict__ bias, float* __restrict__ outF)
{
    __shared__ short As_hi[128 * 32], As_lo[128 * 32];
    __shared__ short Bs_hi[128 * 32], Bs_lo[128 * 32];
    int m0 = (int)(blockIdx.x >> 2) * 128, n0 = (int)(blockIdx.x & 3) * 128;
    gemm_core(As_hi, As_lo, Bs_hi, Bs_lo, Xhi, Xlo, Whi, Wlo, bias, 1.0f, 0,
              outF, nullptr, nullptr, m0, n0);
}

// ---------------------------------------------------------------------------
// RoPE on split-bf16 K, in place, with per-block LDS sin/cos table:
// each block covers 4 rows x 32 freqs -> only 128 sincosf per block
// (threads 0..127), 8x less trig than per-element evaluation.
// ---------------------------------------------------------------------------
__global__ __launch_bounds__(256) void rope_kernel(short* __restrict__ Khi,
                                                   short* __restrict__ Klo)
{
    __shared__ float2 tbl[4][32];
    const int t = threadIdx.x;
    const int g = blockIdx.x * 256 + t;     // 524288 total
    if (t < 128) {
        int p = t >> 5, i = t & 31;
        int pos = (blockIdx.x * 4 + p) & 4095;
        float fr = expf((float)i * -0.28782313662425576f);
        float sv, cv;
        sincosf((float)pos * fr, &sv, &cv);
        tbl[p][i] = make_float2(cv, sv);
    }
    __syncthreads();

    int row = g >> 6;
    int c8  = (g & 63) * 8;
    size_t off = (size_t)row * 512 + c8;
    bf16x8 hi = *(const bf16x8*)&Khi[off];
    bf16x8 lo = *(const bf16x8*)&Klo[off];
    float x[8];
    #pragma unroll
    for (int j = 0; j < 8; ++j)
        x[j] = bf2f((unsigned short)hi[j]) + bf2f((unsigned short)lo[j]);
    const int rl = row & 3;
    const int ib = (c8 & 63) >> 1;
    #pragma unroll
    for (int p = 0; p < 4; ++p) {
        float2 cs = tbl[rl][ib + p];
        float e = x[2 * p], o = x[2 * p + 1];
        x[2 * p]     = e * cs.x - o * cs.y;
        x[2 * p + 1] = o * cs.x + e * cs.y;
    }
    #pragma unroll
    for (int j = 0; j < 8; ++j) {
        unsigned short hb = f2bf(x[j]);
        hi[j] = (short)hb;
        lo[j] = (short)f2bf(x[j] - bf2f(hb));
    }
    *(bf16x8*)&Khi[off] = hi;
    *(bf16x8*)&Klo[off] = lo;
}

// ---------------------------------------------------------------------------
// MFMA flash attention (R9-proven, 90.9 us): wave-private K hi+lo LDS
// staging via global_load_lds double-buffer + explicit vmcnt(0) drain;
// (256,2) — NO higher occupancy cap (spills: R5/R6/R10).
// QK MFMAs all issued before exp; P packed by v_perm truncation; row sums
// via ones-column PV MFMA (truncation bias cancels in normalization).
// ---------------------------------------------------------------------------
__global__ __launch_bounds__(256, 2) void attn_mfma_kernel(
    const short* __restrict__ Qhi, const short* __restrict__ Qlo,
    const short* __restrict__ Khi, const short* __restrict__ Klo,
    const short* __restrict__ Vfrag,
    short* __restrict__ AOhi, short* __restrict__ AOlo)
{
    __shared__ char smem[65536];   // staging: wave*16 KB (2 x 8 KB parity)
                                   // after loop: Opart 4*64*33 f32 + Lpart

    const int tid  = threadIdx.x;
    const int wave = tid >> 6;
    const int lane = tid & 63;
    const int quad = lane >> 4;
    const int l15  = lane & 15;

    const int bh = blockIdx.x & 15;      // XCD-local: blk%8 == h under RR
    const int qt = blockIdx.x >> 4;
    const int b  = bh >> 3, h = bh & 7;
    const int qb = qt * 64;

    // ---- Q as B-fragments (all 64 q rows), hi/lo ----
    bf16x8 qh[4][2], ql[4][2];
    #pragma unroll
    for (int tq = 0; tq < 4; ++tq)
        #pragma unroll
        for (int c = 0; c < 2; ++c) {
            size_t qo = ((size_t)(b * 2048 + qb + tq * 16 + l15)) * 512
                        + h * 64 + c * 32 + quad * 8;
            qh[tq][c] = *(const bf16x8*)&Qhi[qo];
            ql[tq][c] = *(const bf16x8*)&Qlo[qo];
        }

    f32x4 o[4][4];    // [tq][dt] O partials over this wave's kv
    f32x4 lo4[4];     // [tq] row sums (ones-column PV)
    #pragma unroll
    for (int i = 0; i < 4; ++i) {
        lo4[i] = (f32x4){0.f, 0.f, 0.f, 0.f};
        #pragma unroll
        for (int j = 0; j < 4; ++j) o[i][j] = (f32x4){0.f, 0.f, 0.f, 0.f};
    }

    const i32x4 onesw = (i32x4){0x3F803F80, 0x3F803F80, 0x3F803F80, 0x3F803F80};
    const bf16x8 vones = *(const bf16x8*)&onesw;

    // per-lane K global bases (this wave's kv rows)
    const short* kh_p = Khi + ((size_t)(b * 4096 + wave * 16 + l15)) * 512
                        + h * 64 + quad * 8;
    const short* kl_p = Klo + ((size_t)(b * 4096 + wave * 16 + l15)) * 512
                        + h * 64 + quad * 8;
    const short* v_p = Vfrag + ((size_t)(b * 8 + h)) * 32 * 8192
                       + ((size_t)(wave * 4) * 64 + lane) * 8;

    // wave-private staging (shorts): parity p at +p*4096, frag f at +f*512,
    // lane reads at +lane*8.  frag f = s*4 + hilo*2 + c.
    short* sw_base = (short*)smem + wave * 8192;

    // ---- prologue: stage it=0 into parity 0 ----
    #pragma unroll
    for (int s = 0; s < 2; ++s)
        #pragma unroll
        for (int c = 0; c < 2; ++c) {
            gload16(kh_p + (size_t)(s * 64) * 512 + c * 32,
                    sw_base + (s * 4 + c) * 512);
            gload16(kl_p + (size_t)(s * 64) * 512 + c * 32,
                    sw_base + (s * 4 + 2 + c) * 512);
        }

    for (int it = 0; it < 32; ++it) {
        const int parity = it & 1;
        short* kb = sw_base + parity * 4096;

        // drain this wave's staging DMAs (LDS-dest, not auto-waited)
        __builtin_amdgcn_s_waitcnt(0x0F70);   // vmcnt(0)

        bf16x8 k0h[2], k0l[2], k1h[2], k1l[2];
        #pragma unroll
        for (int c = 0; c < 2; ++c) {
            k0h[c] = *(const bf16x8*)(kb + (0 + c) * 512 + lane * 8);
            k0l[c] = *(const bf16x8*)(kb + (2 + c) * 512 + lane * 8);
            k1h[c] = *(const bf16x8*)(kb + (4 + c) * 512 + lane * 8);
            k1l[c] = *(const bf16x8*)(kb + (6 + c) * 512 + lane * 8);
        }

        // V fragment register loads (consumed at PV, end of iter)
        bf16x8 vf[4];
        #pragma unroll
        for (int dt = 0; dt < 4; ++dt)
            vf[dt] = *(const bf16x8*)(v_p + dt * 512);

        // async staging for it+1 into other parity
        if (it + 1 < 32) {
            const short* khn = kh_p + (size_t)(it + 1) * 128 * 512;
            const short* kln = kl_p + (size_t)(it + 1) * 128 * 512;
            short* nb = sw_base + (parity ^ 1) * 4096;
            #pragma unroll
            for (int s = 0; s < 2; ++s)
                #pragma unroll
                for (int c = 0; c < 2; ++c) {
                    gload16(khn + (size_t)(s * 64) * 512 + c * 32,
                            nb + (s * 4 + c) * 512);
                    gload16(kln + (size_t)(s * 64) * 512 + c * 32,
                            nb + (s * 4 + 2 + c) * 512);
                }
        }

        // ---- all QK MFMAs first (both sub-tiles) ----
        f32x4 s0[4], s1[4];
        #pragma unroll
        for (int t = 0; t < 4; ++t) {
            s0[t] = (f32x4){0.f, 0.f, 0.f, 0.f};
            s1[t] = (f32x4){0.f, 0.f, 0.f, 0.f};
        }
        #pragma unroll
        for (int c = 0; c < 2; ++c)
            #pragma unroll
            for (int tq = 0; tq < 4; ++tq) {
                s0[tq] = __builtin_amdgcn_mfma_f32_16x16x32_bf16(k0h[c], qh[tq][c], s0[tq], 0, 0, 0);
                s0[tq] = __builtin_amdgcn_mfma_f32_16x16x32_bf16(k0l[c], qh[tq][c], s0[tq], 0, 0, 0);
                s0[tq] = __builtin_amdgcn_mfma_f32_16x16x32_bf16(k0h[c], ql[tq][c], s0[tq], 0, 0, 0);
            }
        #pragma unroll
        for (int c = 0; c < 2; ++c)
            #pragma unroll
            for (int tq = 0; tq < 4; ++tq) {
                s1[tq] = __builtin_amdgcn_mfma_f32_16x16x32_bf16(k1h[c], qh[tq][c], s1[tq], 0, 0, 0);
                s1[tq] = __builtin_amdgcn_mfma_f32_16x16x32_bf16(k1l[c], qh[tq][c], s1[tq], 0, 0, 0);
                s1[tq] = __builtin_amdgcn_mfma_f32_16x16x32_bf16(k1h[c], ql[tq][c], s1[tq], 0, 0, 0);
            }

        // ---- exp2 + perm-pack + PV (per tq) ----
        #pragma unroll
        for (int tq = 0; tq < 4; ++tq) {
            float e0 = exp2f(s0[tq][0]), e1 = exp2f(s0[tq][1]);
            float e2 = exp2f(s0[tq][2]), e3 = exp2f(s0[tq][3]);
            float e4 = exp2f(s1[tq][0]), e5 = exp2f(s1[tq][1]);
            float e6 = exp2f(s1[tq][2]), e7 = exp2f(s1[tq][3]);
            i32x4 pw;
            pw.x = pack_trunc(e1, e0);
            pw.y = pack_trunc(e3, e2);
            pw.z = pack_trunc(e5, e4);
            pw.w = pack_trunc(e7, e6);
            bf16x8 p8 = *(bf16x8*)&pw;
            #pragma unroll
            for (int dt = 0; dt < 4; ++dt)
                o[tq][dt] = __builtin_amdgcn_mfma_f32_16x16x32_bf16(p8, vf[dt], o[tq][dt], 0, 0, 0);
            lo4[tq] = __builtin_amdgcn_mfma_f32_16x16x32_bf16(p8, vones, lo4[tq], 0, 0, 0);
        }

        v_p += 8192;
    }

    __syncthreads();   // staging LDS dead; reuse as reduction buffers
    float* Opart = (float*)smem;               // [4][64*33]
    float* Lpart = (float*)(smem + 33792);     // [4][64]

    // ---- two-pass cross-wave O reduction (pass 0: d 0..31, pass 1: 32..63) ----
    float inv_save[8];
    #pragma unroll
    for (int pass = 0; pass < 2; ++pass) {
        if (pass) __syncthreads();          // prior reads complete
        #pragma unroll
        for (int tq = 0; tq < 4; ++tq)
            #pragma unroll
            for (int dh = 0; dh < 2; ++dh) {
                int dt = pass * 2 + dh;
                #pragma unroll
                for (int r = 0; r < 4; ++r)
                    Opart[wave * (64 * 33) + (tq * 16 + quad * 4 + r) * 33 + dh * 16 + l15] = o[tq][dt][r];
            }
        if (pass == 0 && l15 == 0) {
            #pragma unroll
            for (int tq = 0; tq < 4; ++tq)
                #pragma unroll
                for (int r = 0; r < 4; ++r)
                    Lpart[wave * 64 + tq * 16 + quad * 4 + r] = lo4[tq][r];
        }
        __syncthreads();
        #pragma unroll
        for (int r = 0; r < 8; ++r) {
            int qq = wave * 16 + r * 2 + (lane >> 5);
            int d  = lane & 31;
            float v = Opart[0 * (64 * 33) + qq * 33 + d] + Opart[1 * (64 * 33) + qq * 33 + d]
                    + Opart[2 * (64 * 33) + qq * 33 + d] + Opart[3 * (64 * 33) + qq * 33 + d];
            float inv;
            if (pass == 0) {
                float l = Lpart[qq] + Lpart[64 + qq] + Lpart[128 + qq] + Lpart[192 + qq];
                inv = 1.0f / l;
                inv_save[r] = inv;
            } else {
                inv = inv_save[r];
            }
            float val = v * inv;
            unsigned short hb = f2bf(val);
            size_t oo = ((size_t)(b * 2048 + qb + qq)) * 512 + h * 64 + pass * 32 + d;
            AOhi[oo] = (short)hb;
            AOlo[oo] = (short)f2bf(val - bf2f(hb));
        }
    }
}

// ---------------------------------------------------------------------------
extern "C" void kernel_launch(void* const* d_in, const int* in_sizes, int n_in,
                              void* d_out, int out_size, void* d_ws, size_t ws_size,
                              hipStream_t stream) {
    const float* q  = (const float*)d_in[0];
    const float* kv = (const float*)d_in[1];
    const float* Wq = (const float*)d_in[2];
    const float* bq = (const float*)d_in[3];
    const float* Wk = (const float*)d_in[4];
    const float* bk = (const float*)d_in[5];
    const float* Wv = (const float*)d_in[6];
    const float* bv = (const float*)d_in[7];
    const float* Wo = (const float*)d_in[8];
    const float* bo = (const float*)d_in[9];
    float* out = (float*)d_out;

    char* ws = (char*)d_ws;
    const size_t MB = 1024 * 1024;
    short* cq_hi  = (short*)(ws + 0 * MB);
    short* cq_lo  = (short*)(ws + 4 * MB);
    short* ckv_hi = (short*)(ws + 8 * MB);
    short* ckv_lo = (short*)(ws + 16 * MB);
    short* wq_hi  = (short*)(ws + 24 * MB); short* wq_lo = wq_hi + 262144;
    short* wk_hi  = (short*)(ws + 25 * MB); short* wk_lo = wk_hi + 262144;
    short* wv_hi  = (short*)(ws + 26 * MB); short* wv_lo = wv_hi + 262144;
    short* wo_hi  = (short*)(ws + 27 * MB); short* wo_lo = wo_hi + 262144;
    short* Qhi    = (short*)(ws + 28 * MB);
    short* Qlo    = (short*)(ws + 32 * MB);
    short* Khi    = (short*)(ws + 36 * MB);
    short* Klo    = (short*)(ws + 44 * MB);
    short* Vfrag  = (short*)(ws + 52 * MB);
    short* AOhi   = (short*)(ws + 0 * MB);   // overlay dead converted-q
    short* AOlo   = (short*)(ws + 4 * MB);

    // 0.125 (1/sqrt(Dh)) * log2(e), so attention exp is a bare exp2.
    const float qscale = 0.18033688011112043f;

    dim3 blk(256);
    convert_split_kernel<<<7168, blk, 0, stream>>>(
        q, kv, Wq, Wk, Wv, Wo,
        cq_hi, cq_lo, ckv_hi, ckv_lo,
        wq_hi, wq_lo, wk_hi, wk_lo, wv_hi, wv_lo, wo_hi, wo_lo);

    fused_qkv_gemm_kernel<<<640, blk, 0, stream>>>(
        cq_hi, cq_lo, ckv_hi, ckv_lo,
        wq_hi, wq_lo, wk_hi, wk_lo, wv_hi, wv_lo,
        bq, bk, bv, qscale,
        Qhi, Qlo, Khi, Klo, Vfrag);

    rope_kernel<<<2048, blk, 0, stream>>>(Khi, Klo);

    attn_mfma_kernel<<<dim3(512), blk, 0, stream>>>(
        Qhi, Qlo, Khi, Klo, Vfrag, AOhi, AOlo);

    gemm_o_kernel<<<128, blk, 0, stream>>>(
        AOhi, AOlo, wo_hi, wo_lo, bo, out);
}